// Round 6
// baseline (323.727 us; speedup 1.0000x reference)
//
#include <hip/hip_runtime.h>

#define EE 512
#define HH 256
#define QQ 1024
#define SS 512
#define NSTEPS 3

// ---------------------------------------------------------------------------
// 32x64 GEMM tile engine (round-5): 256 threads, BK=32, register-prefetch
// double buffering, X-tile k-major. Used by gagg_k and rel_k.
// ---------------------------------------------------------------------------
#define GEMM_SHARED __shared__ float Xs[32][66]; __shared__ float Ws[32][68]

__device__ __forceinline__ void mm_tile(const float* __restrict__ Xrow, int K,
                                        const float* __restrict__ Wcol, int N,
                                        float (*Xs)[66], float (*Ws)[68],
                                        float acc[2][4]) {
    const int tid = threadIdx.x;
    const int r   = tid >> 3;          // 0..31
    const int c4  = (tid & 7) << 2;    // X k-chunk
    const int c8  = (tid & 7) << 3;    // W n-chunk
    const int tx  = tid & 15;
    const int ty2 = (tid >> 4) << 1;   // row pair base

    float4 vx  = *(const float4*)&Xrow[r * K + c4];
    float4 vw0 = *(const float4*)&Wcol[r * N + c8];
    float4 vw1 = *(const float4*)&Wcol[r * N + c8 + 4];

    for (int k0 = 0; k0 < K; k0 += 32) {
        Xs[c4 + 0][r] = vx.x;
        Xs[c4 + 1][r] = vx.y;
        Xs[c4 + 2][r] = vx.z;
        Xs[c4 + 3][r] = vx.w;
        *(float4*)&Ws[r][c8]     = vw0;
        *(float4*)&Ws[r][c8 + 4] = vw1;
        __syncthreads();
        if (k0 + 32 < K) {
            vx  = *(const float4*)&Xrow[r * K + k0 + 32 + c4];
            vw0 = *(const float4*)&Wcol[(k0 + 32 + r) * N + c8];
            vw1 = *(const float4*)&Wcol[(k0 + 32 + r) * N + c8 + 4];
        }
        #pragma unroll
        for (int kk = 0; kk < 32; kk++) {
            float4 b = *(const float4*)&Ws[kk][tx << 2];
            float2 a = *(const float2*)&Xs[kk][ty2];
            acc[0][0] += a.x * b.x; acc[0][1] += a.x * b.y;
            acc[0][2] += a.x * b.z; acc[0][3] += a.x * b.w;
            acc[1][0] += a.y * b.x; acc[1][1] += a.y * b.y;
            acc[1][2] += a.y * b.z; acc[1][3] += a.y * b.w;
        }
        __syncthreads();
    }
}

// ---------------------------------------------------------------------------
// enc_k: fused 2-layer encoder. Block b<96 owns 16 rows of [q;s]:
//   X1row = relu(x @ Wn1 + bn1) kept in LDS, QS = X1row @ Wn2 + bn2.
// Block 96 computes class lists / counts. Grid: 97 x 256.
// Thread layout: tx=tid&63 -> 4 cols (4*tx), ty=tid>>6 -> 4 rows (4*ty).
// LDS x reads are lane-uniform (broadcast, free); W reads coalesced float4.
// ---------------------------------------------------------------------------
__global__ __launch_bounds__(256) void enc_k(const float* __restrict__ qf,
                                             const float* __restrict__ sf,
                                             const float* __restrict__ Wn1,
                                             const float* __restrict__ bn1,
                                             const float* __restrict__ Wn2,
                                             const float* __restrict__ bn2,
                                             float* __restrict__ QS,
                                             const int* __restrict__ y,
                                             float* __restrict__ cntf,
                                             float* __restrict__ invd,
                                             int* __restrict__ cls_cnt,
                                             int* __restrict__ cls_list) {
    const int tid = threadIdx.x;
    const int b = blockIdx.x;
    if (b == 96) {                      // mask statistics
        __shared__ int lc[16];
        if (tid < 16) lc[tid] = 0;
        __syncthreads();
        for (int i = tid; i < SS; i += 256) {
            int c = y[i];
            int slot = atomicAdd(&lc[c], 1);
            cls_list[c * SS + slot] = i;
        }
        __syncthreads();
        if (tid < 16) cls_cnt[tid] = lc[tid];
        for (int i = tid; i < SS; i += 256) {
            float n = (float)(lc[y[i]] - 1);
            cntf[i] = n;
            invd[i] = 1.f / fmaxf(n, 1.f);
        }
        return;
    }
    __shared__ float xs[16][EE];        // 32 KB input rows
    __shared__ float x1s[16][HH + 4];   // 16.6 KB hidden rows
    const int m0 = b << 4;
    const float* src = (m0 < QQ) ? (qf + m0 * EE) : (sf + (m0 - QQ) * EE);
    for (int idx = tid; idx < 16 * (EE / 4); idx += 256) {
        int r = idx >> 7, k4 = (idx & 127) << 2;
        *(float4*)&xs[r][k4] = *(const float4*)&src[r * EE + k4];
    }
    __syncthreads();
    const int tx = tid & 63, ty = tid >> 6;
    const int n4 = tx << 2, r0 = ty << 2;
    float acc[4][4] = {{0,0,0,0},{0,0,0,0},{0,0,0,0},{0,0,0,0}};
    #pragma unroll 8
    for (int k = 0; k < EE; k++) {
        float4 w = *(const float4*)&Wn1[k * HH + n4];
        #pragma unroll
        for (int u = 0; u < 4; u++) {
            float a = xs[r0 + u][k];
            acc[u][0] += a * w.x; acc[u][1] += a * w.y;
            acc[u][2] += a * w.z; acc[u][3] += a * w.w;
        }
    }
    float4 b1 = *(const float4*)&bn1[n4];
    #pragma unroll
    for (int u = 0; u < 4; u++) {
        float4 o;
        o.x = fmaxf(acc[u][0] + b1.x, 0.f);
        o.y = fmaxf(acc[u][1] + b1.y, 0.f);
        o.z = fmaxf(acc[u][2] + b1.z, 0.f);
        o.w = fmaxf(acc[u][3] + b1.w, 0.f);
        *(float4*)&x1s[r0 + u][n4] = o;
    }
    __syncthreads();
    float acc2[4][4] = {{0,0,0,0},{0,0,0,0},{0,0,0,0},{0,0,0,0}};
    #pragma unroll 8
    for (int k = 0; k < HH; k++) {
        float4 w = *(const float4*)&Wn2[k * HH + n4];
        #pragma unroll
        for (int u = 0; u < 4; u++) {
            float a = x1s[r0 + u][k];
            acc2[u][0] += a * w.x; acc2[u][1] += a * w.y;
            acc2[u][2] += a * w.z; acc2[u][3] += a * w.w;
        }
    }
    float4 b2 = *(const float4*)&bn2[n4];
    #pragma unroll
    for (int u = 0; u < 4; u++) {
        float4 o;
        o.x = acc2[u][0] + b2.x; o.y = acc2[u][1] + b2.y;
        o.z = acc2[u][2] + b2.z; o.w = acc2[u][3] + b2.w;
        *(float4*)&QS[(m0 + r0 + u) * HH + n4] = o;
    }
}

// ---------------------------------------------------------------------------
// tile_gemm: out[r][c] = s[lst[base+r]] @ Wp[:, h0+c]  (r<64 rows, c<64 cols,
// K=HH). Rows clamped to cnt-1 (duplicates unused). Self-synced at end of
// each K chunk; caller must sync before reading `out`.
// ---------------------------------------------------------------------------
__device__ __forceinline__ void tile_gemm(const float* __restrict__ s,
                                          const float* __restrict__ Wp,
                                          const int* lst, int base, int cnt,
                                          int h0,
                                          float (*Sk)[36], float (*Wt)[68],
                                          float (*out)[68]) {
    const int tid = threadIdx.x;
    const int tx = tid & 15;
    const int ty4 = (tid >> 4) << 2;
    const int r  = tid >> 3;           // 0..31
    const int k4 = (tid & 7) << 2;
    const int kk8 = tid >> 3;          // 0..31
    const int c8  = (tid & 7) << 3;
    float acc[4][4] = {{0,0,0,0},{0,0,0,0},{0,0,0,0},{0,0,0,0}};
    for (int k0 = 0; k0 < HH; k0 += 32) {
        #pragma unroll
        for (int rr = 0; rr < 2; rr++) {
            int idx = base + r + rr * 32;
            int g = lst[idx < cnt ? idx : cnt - 1];
            *(float4*)&Sk[r + rr * 32][k4] = *(const float4*)&s[g * HH + k0 + k4];
        }
        *(float4*)&Wt[kk8][c8]     = *(const float4*)&Wp[(k0 + kk8) * HH + h0 + c8];
        *(float4*)&Wt[kk8][c8 + 4] = *(const float4*)&Wp[(k0 + kk8) * HH + h0 + c8 + 4];
        __syncthreads();
        #pragma unroll
        for (int kk = 0; kk < 32; kk++) {
            float4 w = *(const float4*)&Wt[kk][tx << 2];
            #pragma unroll
            for (int u = 0; u < 4; u++) {
                float a = Sk[ty4 + u][kk];
                acc[u][0] += a * w.x; acc[u][1] += a * w.y;
                acc[u][2] += a * w.z; acc[u][3] += a * w.w;
            }
        }
        __syncthreads();
    }
    #pragma unroll
    for (int u = 0; u < 4; u++) {
        float4 o = { acc[u][0], acc[u][1], acc[u][2], acc[u][3] };
        *(float4*)&out[ty4 + u][tx << 2] = o;
    }
}

// ---------------------------------------------------------------------------
// step_k: per (h-block hb, class c): A = s_c@W1a[:,h0:+64], B = s_c@W1b[...],
// hsum[i][h0+hh] = sum_{j in c, j!=i} relu(A[i]+bm1+B[j]) — A/B never leave
// LDS. General cnt via 64-row chunking (common path: 1 chunk). Grid (4,16).
// ---------------------------------------------------------------------------
__global__ __launch_bounds__(256) void step_k(const float* __restrict__ s,
                                              const float* __restrict__ W1,
                                              const float* __restrict__ bm1t,
                                              const int* __restrict__ cls_cnt,
                                              const int* __restrict__ cls_list,
                                              float* __restrict__ hsum) {
    __shared__ float Sk[64][36];
    __shared__ float Wt[32][68];
    __shared__ float As[64][68];
    __shared__ float Bs[64][68];
    __shared__ int lst[SS];
    const int tid = threadIdx.x;
    const int c = blockIdx.y;
    const int h0 = blockIdx.x << 6;
    const int cnt = cls_cnt[c];
    if (cnt == 0) return;
    for (int m = tid; m < cnt; m += 256) lst[m] = cls_list[c * SS + m];
    __syncthreads();
    const int hh = tid & 63;
    const int ig = tid >> 6;
    const float bias = bm1t[h0 + hh];

    for (int ib = 0; ib < cnt; ib += 64) {
        tile_gemm(s, W1, lst, ib, cnt, h0, Sk, Wt, As);
        __syncthreads();
        float hacc[16];
        #pragma unroll
        for (int v = 0; v < 16; v++) hacc[v] = 0.f;
        for (int jb = 0; jb < cnt; jb += 64) {
            tile_gemm(s, W1 + HH * HH, lst, jb, cnt, h0, Sk, Wt, Bs);
            __syncthreads();
            const int jn = (cnt - jb < 64) ? (cnt - jb) : 64;
            #pragma unroll 4
            for (int v = 0; v < 16; v++) {
                int il = ig + (v << 2);
                int i = ib + il;
                if (i < cnt) {
                    float a = As[il][hh] + bias;
                    float acc = hacc[v];
                    for (int j = 0; j < jn; j++)
                        acc += fmaxf(a + Bs[j][hh], 0.f);
                    if (i >= jb && i < jb + jn)
                        acc -= fmaxf(a + Bs[i - jb][hh], 0.f);   // self term
                    hacc[v] = acc;
                }
            }
            __syncthreads();
        }
        #pragma unroll
        for (int v = 0; v < 16; v++) {
            int i = ib + ig + (v << 2);
            if (i < cnt)
                hsum[lst[i] * HH + h0 + hh] = hacc[v];
        }
    }
}

// ---------------------------------------------------------------------------
// gagg: s += (hsum@W2 + cnt*bm2) * invden. grid (4, 16).
// ---------------------------------------------------------------------------
__global__ __launch_bounds__(256) void gagg_k(const float* __restrict__ hsum,
                                              const float* __restrict__ W2,
                                              const float* __restrict__ bm2t,
                                              const float* __restrict__ cntf,
                                              const float* __restrict__ invd,
                                              float* __restrict__ s) {
    GEMM_SHARED;
    const int tid = threadIdx.x;
    const int m0 = blockIdx.y << 5;
    const int n0 = blockIdx.x << 6;
    float acc[2][4] = {{0,0,0,0},{0,0,0,0}};
    mm_tile(hsum + m0 * HH, HH, W2 + n0, HH, Xs, Ws, acc);
    const int tx = tid & 15, ty2 = (tid >> 4) << 1;
    #pragma unroll
    for (int rr = 0; rr < 2; rr++) {
        int m = m0 + ty2 + rr;
        int n = n0 + (tx << 2);
        float ci = cntf[m], di = invd[m];
        float* sp = &s[m * HH + n];
        float4 sv = *(float4*)sp;
        float4 o;
        o.x = sv.x + (acc[rr][0] + ci * bm2t[n + 0]) * di;
        o.y = sv.y + (acc[rr][1] + ci * bm2t[n + 1]) * di;
        o.z = sv.z + (acc[rr][2] + ci * bm2t[n + 2]) * di;
        o.w = sv.w + (acc[rr][3] + ci * bm2t[n + 3]) * di;
        *(float4*)sp = o;
    }
}

// ---------------------------------------------------------------------------
// rel: hq = q@Wr1a (by<32); hsT[h][j] = (s@Wr1b)[j][h] + br1[h] (by>=32).
// grid (4, 48).
// ---------------------------------------------------------------------------
__global__ __launch_bounds__(256) void rel_k(const float* __restrict__ q,
                                             const float* __restrict__ s,
                                             const float* __restrict__ Wr1,
                                             const float* __restrict__ br1,
                                             float* __restrict__ hq,
                                             float* __restrict__ hsT) {
    GEMM_SHARED;
    const int tid = threadIdx.x;
    const int n0 = blockIdx.x << 6;
    const int tx = tid & 15, ty2 = (tid >> 4) << 1;
    float acc[2][4] = {{0,0,0,0},{0,0,0,0}};
    if (blockIdx.y < 32) {
        const int m0 = blockIdx.y << 5;
        mm_tile(q + m0 * HH, HH, Wr1 + n0, HH, Xs, Ws, acc);
        #pragma unroll
        for (int rr = 0; rr < 2; rr++) {
            int m = m0 + ty2 + rr;
            int n = n0 + (tx << 2);
            float4 o = { acc[rr][0], acc[rr][1], acc[rr][2], acc[rr][3] };
            *(float4*)&hq[m * HH + n] = o;
        }
    } else {
        const int m0 = (blockIdx.y - 32) << 5;
        mm_tile(s + m0 * HH, HH, Wr1 + HH * HH + n0, HH, Xs, Ws, acc);
        #pragma unroll
        for (int rr = 0; rr < 2; rr++) {
            int m = m0 + ty2 + rr;
            #pragma unroll
            for (int cc = 0; cc < 4; cc++) {
                int n = n0 + (tx << 2) + cc;
                hsT[n * SS + m] = acc[rr][cc] + br1[n];
            }
        }
    }
}

// ---------------------------------------------------------------------------
// scores[i][j] = sum_h relu(hq[i][h] + hsT[h][j]) * wr2[h] + br2
// grid (Q/4, S/256); h chunks of 8 with 8 loads in flight.
// ---------------------------------------------------------------------------
__global__ __launch_bounds__(256) void scores_k(const float* __restrict__ hq,
                                                const float* __restrict__ hsT,
                                                const float* __restrict__ wr2,
                                                const float* __restrict__ br2,
                                                float* __restrict__ out) {
    __shared__ float hqs[4][HH];
    __shared__ float w2s[HH];
    const int tid = threadIdx.x;
    const int i0 = blockIdx.x << 2;
    const int j  = (blockIdx.y << 8) + tid;
    w2s[tid] = wr2[tid];
    #pragma unroll
    for (int ii = 0; ii < 4; ii++) hqs[ii][tid] = hq[(i0 + ii) * HH + tid];
    __syncthreads();
    float acc[4] = {0, 0, 0, 0};
    for (int h0 = 0; h0 < HH; h0 += 8) {
        float v[8];
        #pragma unroll
        for (int u = 0; u < 8; u++) v[u] = hsT[(h0 + u) * SS + j];
        float4 w0 = *(const float4*)&w2s[h0];
        float4 w1 = *(const float4*)&w2s[h0 + 4];
        #pragma unroll
        for (int ii = 0; ii < 4; ii++) {
            float4 a0 = *(const float4*)&hqs[ii][h0];
            float4 a1 = *(const float4*)&hqs[ii][h0 + 4];
            acc[ii] += fmaxf(v[0] + a0.x, 0.f) * w0.x
                     + fmaxf(v[1] + a0.y, 0.f) * w0.y
                     + fmaxf(v[2] + a0.z, 0.f) * w0.z
                     + fmaxf(v[3] + a0.w, 0.f) * w0.w
                     + fmaxf(v[4] + a1.x, 0.f) * w1.x
                     + fmaxf(v[5] + a1.y, 0.f) * w1.y
                     + fmaxf(v[6] + a1.z, 0.f) * w1.z
                     + fmaxf(v[7] + a1.w, 0.f) * w1.w;
        }
    }
    float b2 = br2[0];
    #pragma unroll
    for (int ii = 0; ii < 4; ii++)
        out[(i0 + ii) * SS + j] = acc[ii] + b2;
}

extern "C" void kernel_launch(void* const* d_in, const int* in_sizes, int n_in,
                              void* d_out, int out_size, void* d_ws, size_t ws_size,
                              hipStream_t stream) {
    const float* qf  = (const float*)d_in[0];
    const float* sf  = (const float*)d_in[1];
    const int*   y   = (const int*)d_in[2];
    const float* Wn1 = (const float*)d_in[3];
    const float* bn1 = (const float*)d_in[4];
    const float* Wn2 = (const float*)d_in[5];
    const float* bn2 = (const float*)d_in[6];
    const float* Wm1 = (const float*)d_in[7];
    const float* bm1 = (const float*)d_in[8];
    const float* Wm2 = (const float*)d_in[9];
    const float* bm2 = (const float*)d_in[10];
    const float* Wr1 = (const float*)d_in[11];
    const float* br1 = (const float*)d_in[12];
    const float* wr2 = (const float*)d_in[13];
    const float* br2 = (const float*)d_in[14];
    float* out = (float*)d_out;

    float* F    = (float*)d_ws;
    float* QS   = F + 0;             // 1536*256 (q rows 0..1023, s rows 1024..1535)
    float* q    = QS;
    float* s    = QS + QQ * HH;
    float* hsum = F + 393216;        // 512*256
    float* hq   = F + 524288;        // 1024*256
    float* hsT  = F + 786432;        // 256*512
    float* cntf = F + 917504;        // 512
    float* invd = F + 918016;        // 512
    int*  icls  = (int*)(F + 918528);
    int*  cls_cnt  = icls;           // 16
    int*  cls_list = icls + 16;      // 16*512

    // fused 2-layer encoder + mask statistics (block 96)
    enc_k<<<97, 256, 0, stream>>>(qf, sf, Wn1, bn1, Wn2, bn2, QS,
                                  y, cntf, invd, cls_cnt, cls_list);

    // message passing: per-class fused A/B/hsum, then gemm+aggregate
    for (int t = 0; t < NSTEPS; t++) {
        const float* W1t = Wm1 + t * 2 * HH * HH;
        const float* b1t = bm1 + t * HH;
        const float* W2t = Wm2 + t * HH * HH;
        const float* b2t = bm2 + t * HH;
        step_k<<<dim3(4, 16), 256, 0, stream>>>(s, W1t, b1t, cls_cnt, cls_list, hsum);
        gagg_k<<<dim3(4, 16), 256, 0, stream>>>(hsum, W2t, b2t, cntf, invd, s);
    }

    // relation head
    rel_k<<<dim3(4, 48), 256, 0, stream>>>(q, s, Wr1, br1, hq, hsT);
    scores_k<<<dim3(QQ / 4, SS / 256), 256, 0, stream>>>(hq, hsT, wr2, br2, out);
}